// Round 3
// baseline (89.962 us; speedup 1.0000x reference)
//
#include <hip/hip_runtime.h>

// PatchPooling: out[b,p,d] = mean over s in [fr,to) of batch[b,s,d], empty -> -1.
// B=64, S=1024, D=256, P=64; patch_lengths in [0,16) so cnt <= 15 (wave-uniform).
constexpr int S = 1024;
constexpr int D = 256;
constexpr int P = 64;
constexpr int MAXLEN = 15;
constexpr int WAVES_PER_BLOCK = 4;  // 4 patches per 256-thread block

__global__ __launch_bounds__(256) void patch_pool_kernel(
    const float* __restrict__ batch,
    const int* __restrict__ pl,
    float* __restrict__ out) {
  const int b = blockIdx.x;
  const int wave = threadIdx.x >> 6;
  const int lane = threadIdx.x & 63;
  const int p = blockIdx.y * WAVES_PER_BLOCK + wave;

  // Lane loads one patch length for row b; wave prefix-reduce to get boundary.
  // (Redundant across the 4 waves, but served from L1 after the first.)
  int v = pl[b * P + lane];
  int mylen = __shfl(v, p, 64);            // length of patch p
  int masked = (lane <= p) ? v : 0;
  #pragma unroll
  for (int off = 32; off > 0; off >>= 1)
    masked += __shfl_down(masked, off, 64);
  int to = __shfl(masked, 0, 64);          // inclusive cumsum at p
  int fr = to - mylen;
  int to_c = min(to, S);
  int fr_c = min(fr, S);
  int cnt = min(to_c - fr_c, MAXLEN);      // 0..15, wave-uniform (clamp = OOB guard)

  float4* outp = (float4*)(out + ((size_t)b * P + p) * D) + lane;
  if (cnt <= 0) {
    *outp = make_float4(-1.f, -1.f, -1.f, -1.f);
    return;
  }

  const float4* src = (const float4*)(batch + (size_t)b * S * D) + lane;

  // Issue all (<=15) row loads with no consumer between them; cnt is
  // wave-uniform so the branches don't diverge and loads stay in flight.
  float4 r[MAXLEN];
  #pragma unroll
  for (int i = 0; i < MAXLEN; ++i) {
    r[i] = make_float4(0.f, 0.f, 0.f, 0.f);
    if (i < cnt) r[i] = src[(size_t)(fr_c + i) * (D / 4)];
  }

  float sx = 0.f, sy = 0.f, sz = 0.f, sw = 0.f;
  #pragma unroll
  for (int i = 0; i < MAXLEN; ++i) {
    sx += r[i].x; sy += r[i].y; sz += r[i].z; sw += r[i].w;
  }

  float inv = 1.0f / (float)cnt;
  *outp = make_float4(sx * inv, sy * inv, sz * inv, sw * inv);
}

extern "C" void kernel_launch(void* const* d_in, const int* in_sizes, int n_in,
                              void* d_out, int out_size, void* d_ws, size_t ws_size,
                              hipStream_t stream) {
  const float* batch = (const float*)d_in[0];
  const int* pl = (const int*)d_in[1];
  float* out = (float*)d_out;
  const int B = in_sizes[1] / P;  // 64
  dim3 grid(B, P / WAVES_PER_BLOCK);
  hipLaunchKernelGGL(patch_pool_kernel, grid, dim3(256), 0, stream,
                     batch, pl, out);
}